// Round 1
// baseline (132.270 us; speedup 1.0000x reference)
//
#include <hip/hip_runtime.h>

#define BH   64
#define NTOK 2048
#define DD   128
#define CHK  64
#define NCH  32

typedef __attribute__((ext_vector_type(8))) short bf16x8;
typedef __attribute__((ext_vector_type(4))) float f32x4;
typedef unsigned short u16;

__device__ __forceinline__ u16 f2bf(float f){
  union { float f; unsigned u; } x; x.f = f;
  unsigned r = (x.u + 0x7fffu + ((x.u >> 16) & 1u)) >> 16;
  return (u16)r;
}
__device__ __forceinline__ float bf2f(u16 h){
  union { unsigned u; float f; } x; x.u = ((unsigned)h) << 16;
  return x.f;
}
// XOR-swizzle: permute 16B units within 128B windows by row&7 (kills stride-256B/128B bank conflicts)
__device__ __forceinline__ int swz(int r, int c, int re){
  int b = (r*re + c)*2;
  return b ^ ((r & 7) << 4);
}
__device__ __forceinline__ void lds_w1(u16* a, int r, int c, int re, u16 v){
  *(u16*)((char*)a + swz(r,c,re)) = v;
}
__device__ __forceinline__ void lds_w4(u16* a, int r, int c, int re, ushort4 v){
  *(ushort4*)((char*)a + swz(r,c,re)) = v;
}
__device__ __forceinline__ bf16x8 lds_r8(const u16* a, int r, int c, int re){
  return *(const bf16x8*)((const char*)a + swz(r,c,re));
}

// ---------------- K1: per (head,chunk): U^T = V^T K_bar, A_c = 2^{b_{C-1}} ----------------
__global__ __launch_bounds__(256) void gla_k1(
    const float* __restrict__ Kg, const float* __restrict__ Vg,
    const float* __restrict__ Gg, u16* __restrict__ U, float* __restrict__ Ad)
{
  __shared__ float sb[CHK], sw[CHK];
  __shared__ u16 KbT[DD*CHK];   // K_bar transposed [d][s], swizzled
  __shared__ u16 VbT[DD*CHK];   // V transposed    [e][s], swizzled
  const int tid = threadIdx.x;
  const int bh = blockIdx.x >> 5, c = blockIdx.x & 31;
  const size_t tok0 = (size_t)bh*NTOK + (size_t)c*CHK;

  if (tid < 64){
    float gv = Gg[tok0 + tid];
    float l = 1.f/(1.f + expf(-gv));
    float x = log2f(l);
    #pragma unroll
    for (int off=1; off<64; off<<=1){
      float y = __shfl_up(x, off, 64);
      if (tid >= off) x += y;
    }
    sb[tid] = x;          // inclusive cumsum of log2(l)
    sw[tid] = 1.f - l;
  }
  __syncthreads();
  const float b63 = sb[CHK-1];

  { // stage: k_bar = 2^{b63-b_s}(1-l_s) k_s (transposed), v (transposed), bf16
    const int s = tid >> 2, d0 = (tid & 3) * 32;
    const float ck = exp2f(b63 - sb[s]) * sw[s];
    const float4* kp = (const float4*)(Kg + (tok0 + s)*DD + d0);
    const float4* vp = (const float4*)(Vg + (tok0 + s)*DD + d0);
    #pragma unroll
    for (int i=0;i<8;++i){
      float4 kf = kp[i], vf = vp[i];
      int d = d0 + i*4;
      lds_w1(KbT, d+0, s, CHK, f2bf(kf.x*ck));
      lds_w1(KbT, d+1, s, CHK, f2bf(kf.y*ck));
      lds_w1(KbT, d+2, s, CHK, f2bf(kf.z*ck));
      lds_w1(KbT, d+3, s, CHK, f2bf(kf.w*ck));
      lds_w1(VbT, d+0, s, CHK, f2bf(vf.x));
      lds_w1(VbT, d+1, s, CHK, f2bf(vf.y));
      lds_w1(VbT, d+2, s, CHK, f2bf(vf.z));
      lds_w1(VbT, d+3, s, CHK, f2bf(vf.w));
    }
  }
  __syncthreads();

  const int w = tid >> 6, l = tid & 63, lr = l & 15, lh = l >> 4;
  f32x4 acc[2][8] = {};
  #pragma unroll
  for (int ks=0; ks<2; ++ks){
    const int kk = ks*32 + lh*8;
    bf16x8 a0 = lds_r8(VbT, w*32 + lr,      kk, CHK);
    bf16x8 a1 = lds_r8(VbT, w*32 + 16 + lr, kk, CHK);
    #pragma unroll
    for (int n=0;n<8;++n){
      bf16x8 bb = lds_r8(KbT, n*16 + lr, kk, CHK);
      acc[0][n] = __builtin_amdgcn_mfma_f32_16x16x32_bf16(a0, bb, acc[0][n], 0,0,0);
      acc[1][n] = __builtin_amdgcn_mfma_f32_16x16x32_bf16(a1, bb, acc[1][n], 0,0,0);
    }
  }

  u16* Ug = U + ((size_t)blockIdx.x << 14);   // [e][d] bf16
  #pragma unroll
  for (int mi=0;mi<2;++mi)
    #pragma unroll
    for (int n=0;n<8;++n)
      #pragma unroll
      for (int r=0;r<4;++r){
        int e = w*32 + mi*16 + lh*4 + r;
        int d = n*16 + lr;
        Ug[e*DD + d] = f2bf(acc[mi][n][r]);
      }
  if (tid == 0) Ad[blockIdx.x] = exp2f(b63);
}

// ---------------- K2: elementwise chunk scan, in-place: U[c] <- S_before_chunk_c ----------------
__global__ __launch_bounds__(256) void gla_k2(u16* __restrict__ U, const float* __restrict__ Ad)
{
  const int flat = blockIdx.x * 256 + threadIdx.x;
  const int bh  = flat >> 14;
  const int idx = flat & 16383;
  u16* p = U + ((size_t)bh << 19) + idx;
  const float* Ab = Ad + bh*NCH;
  float S = 0.f;
  #pragma unroll 4
  for (int c=0;c<NCH;++c){
    float u = bf2f(p[(size_t)c << 14]);
    p[(size_t)c << 14] = f2bf(S);
    S = fmaf(Ab[c], S, u);
  }
}

// ---------------- K3: O = Qt * S_in + tril(Qt Kh^T) V ----------------
__global__ __launch_bounds__(256) void gla_k3(
    const float* __restrict__ Qg, const float* __restrict__ Kg,
    const float* __restrict__ Vg, const float* __restrict__ Gg,
    const u16* __restrict__ Sp, float* __restrict__ Og)
{
  __shared__ float sb[CHK], sw[CHK];
  __shared__ u16 Qb[CHK*DD];    // q~ row-major [t][d], swizzled
  __shared__ u16 buf[DD*DD];    // phase1: S^T [e][d]; phase2: Kh[64][128] + VT[128][64]
  __shared__ u16 Pb[CHK*CHK];   // masked P bf16 [t][s], swizzled
  const int tid = threadIdx.x;
  const int bh = blockIdx.x >> 5, c = blockIdx.x & 31;
  const size_t tok0 = (size_t)bh*NTOK + (size_t)c*CHK;

  if (tid < 64){
    float gv = Gg[tok0 + tid];
    float l = 1.f/(1.f + expf(-gv));
    float x = log2f(l);
    #pragma unroll
    for (int off=1; off<64; off<<=1){
      float y = __shfl_up(x, off, 64);
      if (tid >= off) x += y;
    }
    sb[tid] = x;
    sw[tid] = 1.f - l;
  }
  __syncthreads();

  const int rw = tid >> 2, d0 = (tid & 3)*32;
  { // stage Qb = 2^{b_t} q_t
    const float cq = exp2f(sb[rw]);
    const float4* qp = (const float4*)(Qg + (tok0 + rw)*DD + d0);
    #pragma unroll
    for (int i=0;i<8;++i){
      float4 f = qp[i];
      ushort4 u4 = make_ushort4(f2bf(f.x*cq), f2bf(f.y*cq), f2bf(f.z*cq), f2bf(f.w*cq));
      lds_w4(Qb, rw, d0 + i*4, DD, u4);
    }
  }
  { // stage S^T (bf16 from ws)
    const int e = tid >> 1, dd = (tid & 1)*64;
    const ushort4* sp4 = (const ushort4*)(Sp + ((size_t)blockIdx.x << 14) + e*DD + dd);
    #pragma unroll
    for (int i=0;i<16;++i) lds_w4(buf, e, dd + i*4, DD, sp4[i]);
  }
  __syncthreads();

  const int w = tid >> 6, l = tid & 63, lr = l & 15, lh = l >> 4;
  f32x4 acc[8] = {};
  #pragma unroll
  for (int ks=0;ks<4;++ks){   // O1 = Qt * S_in   (K = 128)
    const int kk = ks*32 + lh*8;
    bf16x8 a = lds_r8(Qb, w*16 + lr, kk, DD);
    #pragma unroll
    for (int n=0;n<8;++n){
      bf16x8 bb = lds_r8(buf, n*16 + lr, kk, DD);
      acc[n] = __builtin_amdgcn_mfma_f32_16x16x32_bf16(a, bb, acc[n], 0,0,0);
    }
  }
  __syncthreads();

  // stage Kh = 2^{-b_s}(1-l_s) k_s (row-major) and V^T
  u16* Kh = buf;
  u16* VT = buf + CHK*DD;
  {
    const float chk = exp2f(-sb[rw]) * sw[rw];
    const float4* kp = (const float4*)(Kg + (tok0 + rw)*DD + d0);
    const float4* vp = (const float4*)(Vg + (tok0 + rw)*DD + d0);
    #pragma unroll
    for (int i=0;i<8;++i){
      float4 kf = kp[i], vf = vp[i];
      int d = d0 + i*4;
      ushort4 u4 = make_ushort4(f2bf(kf.x*chk), f2bf(kf.y*chk), f2bf(kf.z*chk), f2bf(kf.w*chk));
      lds_w4(Kh, rw, d, DD, u4);
      lds_w1(VT, d+0, rw, CHK, f2bf(vf.x));
      lds_w1(VT, d+1, rw, CHK, f2bf(vf.y));
      lds_w1(VT, d+2, rw, CHK, f2bf(vf.z));
      lds_w1(VT, d+3, rw, CHK, f2bf(vf.w));
    }
  }
  __syncthreads();

  f32x4 pacc[4] = {};
  #pragma unroll
  for (int ks=0;ks<4;++ks){   // P = Qt * Kh^T   (64x64, K = 128)
    const int kk = ks*32 + lh*8;
    bf16x8 a = lds_r8(Qb, w*16 + lr, kk, DD);
    #pragma unroll
    for (int n=0;n<4;++n){
      bf16x8 bb = lds_r8(Kh, n*16 + lr, kk, DD);
      pacc[n] = __builtin_amdgcn_mfma_f32_16x16x32_bf16(a, bb, pacc[n], 0,0,0);
    }
  }
  #pragma unroll
  for (int n=0;n<4;++n)       // causal mask (s <= t) + bf16 to LDS
    #pragma unroll
    for (int r=0;r<4;++r){
      int tt = w*16 + lh*4 + r;
      int ss = n*16 + lr;
      float pv = (ss <= tt) ? pacc[n][r] : 0.f;
      lds_w1(Pb, tt, ss, CHK, f2bf(pv));
    }
  __syncthreads();

  #pragma unroll
  for (int ks=0;ks<2;++ks){   // O += P * V   (K = 64)
    const int kk = ks*32 + lh*8;
    bf16x8 a = lds_r8(Pb, w*16 + lr, kk, CHK);
    #pragma unroll
    for (int n=0;n<8;++n){
      bf16x8 bb = lds_r8(VT, n*16 + lr, kk, CHK);
      acc[n] = __builtin_amdgcn_mfma_f32_16x16x32_bf16(a, bb, acc[n], 0,0,0);
    }
  }

  float* Op = Og + tok0*DD;
  #pragma unroll
  for (int n=0;n<8;++n)
    #pragma unroll
    for (int r=0;r<4;++r){
      int tt = w*16 + lh*4 + r;
      int e  = n*16 + lr;
      Op[tt*DD + e] = acc[n][r];
    }
}

extern "C" void kernel_launch(void* const* d_in, const int* in_sizes, int n_in,
                              void* d_out, int out_size, void* d_ws, size_t ws_size,
                              hipStream_t stream)
{
  const float* q = (const float*)d_in[0];
  const float* k = (const float*)d_in[1];
  const float* v = (const float*)d_in[2];
  const float* g = (const float*)d_in[3];
  float* out = (float*)d_out;
  u16*   U   = (u16*)d_ws;                                       // 64 MB: [bh][c][e][d] bf16
  float* Ad  = (float*)((char*)d_ws + (size_t)BH*NCH*DD*DD*2);   // 8 KB: per-chunk decay

  gla_k1<<<dim3(BH*NCH), dim3(256), 0, stream>>>(k, v, g, U, Ad);
  gla_k2<<<dim3(BH*DD*DD/256), dim3(256), 0, stream>>>(U, Ad);
  gla_k3<<<dim3(BH*NCH), dim3(256), 0, stream>>>(q, k, v, g, U, out);
}

// Round 2
// 121.982 us; speedup vs baseline: 1.0843x; 1.0843x over previous
//
#include <hip/hip_runtime.h>

#define NTOK 2048
#define DD   128
#define CHK  64
#define NCH  32
#define EW   32

typedef __attribute__((ext_vector_type(8))) short bf16x8;
typedef __attribute__((ext_vector_type(4))) float f32x4;
typedef unsigned short u16;
typedef unsigned int u32;

#define MFMA(a,b,c) __builtin_amdgcn_mfma_f32_16x16x32_bf16(a,b,c,0,0,0)

__device__ __forceinline__ u16 f2bf(float f){
  union { float f; unsigned u; } x; x.f = f;
  return (u16)((x.u + 0x7fffu + ((x.u >> 16) & 1u)) >> 16);
}
// XOR-swizzle 16B units within 128B windows by row&7
__device__ __forceinline__ int swz(int r, int c, int re){
  int b = (r*re + c)*2;
  return b ^ ((r & 7) << 4);
}
__device__ __forceinline__ void lds_w1(u16* a, int r, int c, int re, u16 v){
  *(u16*)((char*)a + swz(r,c,re)) = v;
}
__device__ __forceinline__ void lds_w4(u16* a, int r, int c, int re, ushort4 v){
  *(ushort4*)((char*)a + swz(r,c,re)) = v;
}
__device__ __forceinline__ bf16x8 lds_r8(const u16* a, int r, int c, int re){
  return *(const bf16x8*)((const char*)a + swz(r,c,re));
}
__device__ __forceinline__ void gld16(const float* g, float* l){
  __builtin_amdgcn_global_load_lds((const __attribute__((address_space(1))) u32*)g,
                                   (__attribute__((address_space(3))) u32*)l, 16, 0, 0);
}
__device__ __forceinline__ void gld4(const float* g, float* l){
  __builtin_amdgcn_global_load_lds((const __attribute__((address_space(1))) u32*)g,
                                   (__attribute__((address_space(3))) u32*)l, 4, 0, 0);
}

__global__ __launch_bounds__(256) void gla_fused(
    const float* __restrict__ Qg, const float* __restrict__ Kg,
    const float* __restrict__ Vg, const float* __restrict__ Gg,
    float* __restrict__ Og)
{
  __shared__ float Kraw[CHK*DD];   // raw K chunk (next), source-swizzled
  __shared__ float Vraw[CHK*EW];   // raw V slice (next), source-swizzled
  __shared__ float Graw[CHK];
  __shared__ u16 Kh [CHK*DD];      // K_hat [s][d], swz
  __shared__ u16 KhT[DD*CHK];      // K_hat^T [d][s], swz
  __shared__ u16 VT [EW*CHK];      // V^T [e][s], swz
  __shared__ u16 ST [EW*DD];       // S^T [e][d], swz (bf16 snapshot of S regs)
  __shared__ u16 Pb [CHK*CHK];     // masked P [t][s], swz

  const int tid = threadIdx.x;
  const int w = tid >> 6, l = tid & 63, lr = l & 15, lh = l >> 4;
  // XCD-swizzle: 4 sibling e-slices of one head land on the same XCD (share its L2)
  const int slot = blockIdx.x >> 3;
  const int bh = (blockIdx.x & 7) + 8*(slot >> 2);
  const int e0 = (slot & 3) * EW;

  const float* Qh  = Qg + (size_t)bh*NTOK*DD;
  const float* Kgh = Kg + (size_t)bh*NTOK*DD;
  const float* Vh  = Vg + (size_t)bh*NTOK*DD;
  const float* Gh  = Gg + (size_t)bh*NTOK;
  float* Oh = Og + (size_t)bh*NTOK*DD;

  f32x4 S00 = {}, S01 = {}, S10 = {}, S11 = {};   // S[d][e] slice, MFMA C-layout
  float4 qpre[8];

  auto prefetch = [&](int c){
    const int t0 = c*CHK;
    #pragma unroll
    for (int i=0;i<8;++i){        // K chunk: 2048 16B-units, src col pre-swizzled
      int u = i*256 + tid;
      int s = u >> 5, cu = u & 31;
      int src = (cu & 24) | ((cu & 7) ^ (s & 7));
      gld16(Kgh + (size_t)(t0+s)*DD + src*4, Kraw + u*4);
    }
    #pragma unroll
    for (int i=0;i<2;++i){        // V slice: 512 16B-units
      int u = i*256 + tid;
      int s = u >> 3, sub = u & 7;
      gld16(Vh + (size_t)(t0+s)*DD + e0 + ((sub ^ (s&7))*4), Vraw + u*4);
    }
    if (w == 0) gld4(Gh + t0 + l, Graw + l);
    const float* qp = Qh + (size_t)(t0 + w*16 + lr)*DD + lh*8;
    #pragma unroll
    for (int ks=0;ks<4;++ks){     // Q A-fragments straight to regs
      qpre[ks*2]   = *(const float4*)(qp + ks*32);
      qpre[ks*2+1] = *(const float4*)(qp + ks*32 + 4);
    }
  };

  prefetch(0);

  for (int c=0; c<NCH; ++c){
    __syncthreads();   // drains vmcnt: raw[c]+qpre ready; bf16 bufs free

    // gate math, redundantly in every wave (no LDS, no extra barrier)
    float gv = Graw[l];
    float li = 1.f/(1.f + expf(-gv));
    float x  = log2f(li);
    #pragma unroll
    for (int off=1; off<64; off<<=1){
      float y = __shfl_up(x, off, 64);
      if (l >= off) x += y;
    }
    const float bl  = x;                              // b_t at t=l (inclusive cumsum)
    const float ckl = exp2f(-bl) * (1.f - li);        // k-hat scale for row s=l
    const float cq  = exp2f(__shfl(bl, w*16 + lr, 64));
    const float scc = exp2f(__shfl(bl, 63, 64));      // 2^{b_63}

    // ---- convert K -> Kh, KhT ----
    #pragma unroll
    for (int i=0;i<8;++i){
      float4 kf = *(const float4*)(Kraw + l*DD + w*32 + ((i ^ (l&7)) * 4));
      int d = w*32 + i*4;
      u16 b0=f2bf(kf.x*ckl), b1=f2bf(kf.y*ckl), b2=f2bf(kf.z*ckl), b3=f2bf(kf.w*ckl);
      lds_w4(Kh, l, d, DD, make_ushort4(b0,b1,b2,b3));
      lds_w1(KhT, d+0, l, CHK, b0);
      lds_w1(KhT, d+1, l, CHK, b1);
      lds_w1(KhT, d+2, l, CHK, b2);
      lds_w1(KhT, d+3, l, CHK, b3);
    }
    // ---- convert V -> VT ----
    #pragma unroll
    for (int j=0;j<2;++j){
      float4 vf = *(const float4*)(Vraw + l*EW + (((w*2+j) ^ (l&7)) * 4));
      int e = w*8 + j*4;
      lds_w1(VT, e+0, l, CHK, f2bf(vf.x));
      lds_w1(VT, e+1, l, CHK, f2bf(vf.y));
      lds_w1(VT, e+2, l, CHK, f2bf(vf.z));
      lds_w1(VT, e+3, l, CHK, f2bf(vf.w));
    }
    // ---- snapshot S -> ST (bf16) ----
    {
      const int dbase = w*32 + lh*4;
      #pragma unroll
      for (int r=0;r<4;++r){
        lds_w1(ST, lr,    dbase + r,      DD, f2bf(S00[r]));
        lds_w1(ST, 16+lr, dbase + r,      DD, f2bf(S01[r]));
        lds_w1(ST, lr,    dbase + 16 + r, DD, f2bf(S10[r]));
        lds_w1(ST, 16+lr, dbase + 16 + r, DD, f2bf(S11[r]));
      }
    }
    // ---- qA fragments ----
    bf16x8 qA[4];
    #pragma unroll
    for (int ks=0;ks<4;++ks){
      float4 a = qpre[ks*2], b = qpre[ks*2+1];
      bf16x8 t;
      t[0]=(short)f2bf(a.x*cq); t[1]=(short)f2bf(a.y*cq);
      t[2]=(short)f2bf(a.z*cq); t[3]=(short)f2bf(a.w*cq);
      t[4]=(short)f2bf(b.x*cq); t[5]=(short)f2bf(b.y*cq);
      t[6]=(short)f2bf(b.z*cq); t[7]=(short)f2bf(b.w*cq);
      qA[ks] = t;
    }
    __syncthreads();   // bf16 bufs ready; raw free -> start next prefetch
    if (c+1 < NCH) prefetch(c+1);

    // ---- O1 = Qt*S_in ; P = Qt*Kh^T ----
    f32x4 oacc0 = {}, oacc1 = {};
    f32x4 p0 = {}, p1 = {}, p2 = {}, p3 = {};
    #pragma unroll
    for (int ks=0;ks<4;++ks){
      const int kk = ks*32 + lh*8;
      bf16x8 a = qA[ks];
      oacc0 = MFMA(a, lds_r8(ST, lr,    kk, DD), oacc0);
      oacc1 = MFMA(a, lds_r8(ST, 16+lr, kk, DD), oacc1);
      p0 = MFMA(a, lds_r8(Kh, lr,    kk, DD), p0);
      p1 = MFMA(a, lds_r8(Kh, 16+lr, kk, DD), p1);
      p2 = MFMA(a, lds_r8(Kh, 32+lr, kk, DD), p2);
      p3 = MFMA(a, lds_r8(Kh, 48+lr, kk, DD), p3);
    }
    // ---- causal mask -> Pb ----
    {
      const int t = w*16 + lh*4;
      #pragma unroll
      for (int r=0;r<4;++r){
        int tt = t + r;
        lds_w1(Pb, tt, lr,    CHK, f2bf((lr    <= tt) ? p0[r] : 0.f));
        lds_w1(Pb, tt, 16+lr, CHK, f2bf((16+lr <= tt) ? p1[r] : 0.f));
        lds_w1(Pb, tt, 32+lr, CHK, f2bf((32+lr <= tt) ? p2[r] : 0.f));
        lds_w1(Pb, tt, 48+lr, CHK, f2bf((48+lr <= tt) ? p3[r] : 0.f));
      }
    }
    __syncthreads();   // Pb ready

    // ---- O2 += P*V ; W = Khat^T * V accumulated into S ----
    #pragma unroll
    for (int k2=0;k2<2;++k2){
      const int kk = k2*32 + lh*8;
      bf16x8 vb0 = lds_r8(VT, lr,    kk, CHK);
      bf16x8 vb1 = lds_r8(VT, 16+lr, kk, CHK);
      bf16x8 pa  = lds_r8(Pb, w*16 + lr, kk, CHK);
      oacc0 = MFMA(pa, vb0, oacc0);
      oacc1 = MFMA(pa, vb1, oacc1);
      bf16x8 ka0 = lds_r8(KhT, w*32 + lr,      kk, CHK);
      bf16x8 ka1 = lds_r8(KhT, w*32 + 16 + lr, kk, CHK);
      S00 = MFMA(ka0, vb0, S00);
      S01 = MFMA(ka0, vb1, S01);
      S10 = MFMA(ka1, vb0, S10);
      S11 = MFMA(ka1, vb1, S11);
    }
    // S_new = 2^{b63} * (S_old + Khat^T V)
    #pragma unroll
    for (int r=0;r<4;++r){ S00[r]*=scc; S01[r]*=scc; S10[r]*=scc; S11[r]*=scc; }

    // ---- write O chunk (fp32) ----
    {
      float* op = Oh + (size_t)(c*CHK + w*16 + lh*4)*DD + e0;
      #pragma unroll
      for (int r=0;r<4;++r){
        op[r*DD + lr]      = oacc0[r];
        op[r*DD + 16 + lr] = oacc1[r];
      }
    }
  }
}

extern "C" void kernel_launch(void* const* d_in, const int* in_sizes, int n_in,
                              void* d_out, int out_size, void* d_ws, size_t ws_size,
                              hipStream_t stream)
{
  const float* q = (const float*)d_in[0];
  const float* k = (const float*)d_in[1];
  const float* v = (const float*)d_in[2];
  const float* g = (const float*)d_in[3];
  float* out = (float*)d_out;

  gla_fused<<<dim3(256), dim3(256), 0, stream>>>(q, k, v, g, out);
}